// Round 4
// baseline (138.529 us; speedup 1.0000x reference)
//
#include <hip/hip_runtime.h>
#include <stdint.h>

// Bit-exact f32 vs numpy reference required for label thresholds:
// kill FMA contraction everywhere.
#pragma clang fp contract(off)

#define NB 16       // batch
#define NA 12       // anchors per cell
#define NH 64
#define NW 64
#define NG 64       // gt boxes per batch
#define NN (NA*NH*NW)   // 49152 anchors per batch row
#define NBLK (NN/256)   // 192 k_main blocks per batch row
#define NBIN 4096   // rank histogram bins (top 12 of 23 rank bits)
#define CAP 1024    // boundary-bin list capacity per row (expected ~9)

// ws layout (uint32 index) — nothing needs pre-zeroing:
// [0 .. 3072)      per-block packed (pos<<16 | neg) partials (all written by k_main)
// [4096 .. 4096+NB*NN)  rnk32 = (u23<<2)|lab2 per anchor (all written by k_main)
#define WS_PART 0
#define WS_RNK  4096
#define WS_NEED (((size_t)WS_RNK + (size_t)NB*NN) * 4)

__device__ __forceinline__ uint32_t rotl32(uint32_t x, int r) {
    return (x << r) | (x >> (32 - r));
}

// threefry2x32, key = jax.random.key(42) -> (0, 42), partitionable counters:
// x0 = hi(flat_idx)=0, x1 = lo(flat_idx)=i; 32-bit draw = out0 ^ out1.
// Verified bit-exact (absmax 0 in R1-R3).
__device__ uint32_t threefry_bits(uint32_t idx) {
    const uint32_t ks0 = 0u, ks1 = 42u, ks2 = 0x1BD11BDAu ^ 0u ^ 42u;
    uint32_t x0 = ks0;
    uint32_t x1 = idx + ks1;
#define RND(r) { x0 += x1; x1 = rotl32(x1, r); x1 ^= x0; }
    RND(13) RND(15) RND(26) RND(6)
    x0 += ks1; x1 += ks2 + 1u;
    RND(17) RND(29) RND(16) RND(24)
    x0 += ks2; x1 += ks0 + 2u;
    RND(13) RND(15) RND(26) RND(6)
    x0 += ks0; x1 += ks1 + 3u;
    RND(17) RND(29) RND(16) RND(24)
    x0 += ks1; x1 += ks2 + 4u;
    RND(13) RND(15) RND(26) RND(6)
    x0 += ks2; x1 += ks0 + 5u;
#undef RND
    return x0 ^ x1;
}

// Division-free argmax (verified bit-exact R1-R3): fractions (num, den),
// ov==0 represented exactly as 1e-10/1; cross-mult compare with 2^-20 guard
// band, rare in-band fallback does the two IEEE divisions.
__global__ __launch_bounds__(256) void k_main(const float4* __restrict__ gt,
                                              const float4* __restrict__ anc,
                                              float* __restrict__ out,
                                              uint32_t* __restrict__ w,
                                              uint32_t* __restrict__ rnk) {
#pragma clang fp contract(off)
    const int b = blockIdx.y;
    const int n = blockIdx.x * 256 + threadIdx.x;
    const int t = threadIdx.x;

    __shared__ float4 sgv[NG];    // (gx0, gy0, gx1, gy1)
    __shared__ float  sgar[NG];   // gt area
    __shared__ float4 sg0[NG];    // batch-0 boxes (reference gt_flat indexing bug)
    __shared__ float  sout[256 * 5];
    __shared__ uint32_t sred[4];  // per-wave packed (pos<<16 | neg)
    if (t < NG) {
        float4 g = gt[b * NG + t];
        sgv[t] = make_float4(g.x, g.y, g.x + g.z, g.y + g.w);
        sgar[t] = g.z * g.w;
    } else if (t < 2 * NG) {
        sg0[t - NG] = gt[t - NG];
    }
    __syncthreads();

    float4 a = anc[n];
    float ax1 = a.x + a.z;
    float ay1 = a.y + a.w;
    float aar = a.z * a.w;
    bool keep = (a.x >= 0.f) && (a.y >= 0.f) && (a.z >= 0.f) && (a.w >= 0.f)
             && (a.x <= 63.f) && (a.y <= 63.f)
             && ((ax1 - 1.0f) <= 63.f) && ((ay1 - 1.0f) <= 63.f);

    float nb_, db_;            // best fraction
    int ib_ = 0;
    {
        float4 gv = sgv[0];
        float iw = fmaxf(0.0f, fminf(ax1, gv.z) - fmaxf(a.x, gv.x));
        float ih = fmaxf(0.0f, fminf(ay1, gv.w) - fmaxf(a.y, gv.y));
        float inter = iw * ih;
        float uni = (aar + sgar[0]) - inter;
        nb_ = inter; db_ = uni;
        if (inter == 0.0f) { nb_ = 1e-10f; db_ = 1.0f; }
    }
#pragma unroll 4
    for (int g = 1; g < NG; ++g) {
        float4 gv = sgv[g];
        float iw = fmaxf(0.0f, fminf(ax1, gv.z) - fmaxf(a.x, gv.x));
        float ih = fmaxf(0.0f, fminf(ay1, gv.w) - fmaxf(a.y, gv.y));
        float inter = iw * ih;
        float uni = (aar + sgar[g]) - inter;
        float ng_ = inter, dg_ = uni;
        if (inter == 0.0f) { ng_ = 1e-10f; dg_ = 1.0f; }

        float p = ng_ * db_;
        float q = nb_ * dg_;
        float d_ = p - q;
        float band = 0x1p-20f * fmaxf(p, q);
        bool same = (ng_ == nb_) && (dg_ == db_);
        bool nearby = (!same) && (fabsf(d_) <= band);
        bool win;
        if (__builtin_expect(nearby, 0)) {
            float ovg = ng_ / dg_;
            float ovb = nb_ / db_;
            win = ovg > ovb;                        // rounded compare, tie keeps earlier
        } else {
            win = d_ > band;                        // same => d_==0 => false (keep earlier)
        }
        if (win) { nb_ = ng_; db_ = dg_; ib_ = g; }
    }
    float best = nb_ / db_;    // == reference max_ov, bit-exact

    float label = -1.0f;
    if (keep) label = (best >= 0.7f) ? 1.0f : ((best <= 0.3f) ? 0.0f : -1.0f);

    // pos/neg: ballot + LDS combine + one plain store per block (R3 win).
    uint64_t bp = __ballot(keep && (best > 0.7f));   // pos (strict >)
    uint64_t bn = __ballot(keep && (best < 0.3f));   // neg (strict <)
    if ((t & 63) == 0)
        sred[t >> 6] = ((uint32_t)__popcll(bp) << 16) | (uint32_t)__popcll(bn);

    float t0 = 0.f, t1 = 0.f, t2 = 0.f, t3 = 0.f;
    if (keep) {
        float4 g0 = sg0[ib_];                 // always batch-0 (ref bug)
        t0 = a.x - g0.x / 16.0f;
        t1 = a.y - g0.y / 16.0f;
        t2 = a.z - g0.z / 16.0f;
        t3 = a.w - g0.w / 16.0f;
    }

    // Stage to LDS (stride 5, coprime with 32 banks), then coalesced stores.
    sout[t * 5 + 0] = label;
    sout[t * 5 + 1] = t0; sout[t * 5 + 2] = t1;
    sout[t * 5 + 3] = t2; sout[t * 5 + 4] = t3;

    if (rnk) {
        uint32_t u = threefry_bits((uint32_t)(b * NN + n)) >> 9;  // 23-bit rank key
        uint32_t lab2 = (label == 0.0f) ? 2u : ((label == 1.0f) ? 1u : 0u);
        rnk[b * NN + n] = (u << 2) | lab2;
    }

    __syncthreads();
    if (t == 0)
        w[WS_PART + b * NBLK + blockIdx.x] = sred[0] + sred[1] + sred[2] + sred[3];
    float* ob = out + ((size_t)b * NN + (size_t)blockIdx.x * 256) * 5;
#pragma unroll
    for (int k = 0; k < 5; ++k) ob[k * 256 + t] = sout[k * 256 + t];
}

// One block per batch row does: partials->pos/neg, LDS hist, scan->threshold
// bin, disable pass, boundary-bin exact resolve. No cross-block dependencies.
__global__ __launch_bounds__(1024) void k_post(float* __restrict__ out,
                                               const uint32_t* __restrict__ w,
                                               const uint32_t* __restrict__ rnk) {
    const int b = blockIdx.x;
    const int t = threadIdx.x;
    __shared__ uint32_t hist[NBIN];            // 16 KB
    __shared__ uint32_t rp[1024], rn[1024];    // 8 KB
    __shared__ uint32_t lu[CAP], ln[CAP];      // 8 KB boundary list
    __shared__ uint32_t scnt;
    __shared__ int sT;
    __shared__ uint32_t sBase;
    __shared__ uint32_t csum[256];

    // 1. pos/neg from the 3072 packed partials (redundant per block, cheap).
    uint32_t sp = 0, sn = 0;
    for (int i = t; i < NB * NBLK; i += 1024) {
        uint32_t v = w[WS_PART + i];
        sp += v >> 16; sn += v & 0xFFFFu;
    }
    rp[t] = sp; rn[t] = sn;
    if (t == 0) scnt = 0;
    __syncthreads();
    for (int s = 512; s > 0; s >>= 1) {
        if (t < s) { rp[t] += rp[t + s]; rn[t] += rn[t + s]; }
        __syncthreads();
    }
    uint32_t pos = rp[0], neg = rn[0];
    uint32_t cutoff = 3u * pos; if (cutoff < 1u) cutoff = 1u;
    if (neg <= cutoff) return;     // uniform across grid: no disabling at all

    // 2. histogram of 23-bit rank keys (top 12 bits) for label-0 anchors.
    for (int i = t; i < NBIN; i += 1024) hist[i] = 0;
    __syncthreads();
    for (int i = t; i < NN; i += 1024) {
        uint32_t idx = (uint32_t)(b * NN + i);
        if (rnk) {
            uint32_t v = rnk[idx];
            if ((v & 3u) == 2u) atomicAdd(&hist[(v >> 2) >> 11], 1u);
        } else {
            if (out[(size_t)idx * 5] == 0.0f) {
                uint32_t u = threefry_bits(idx) >> 9;
                atomicAdd(&hist[u >> 11], 1u);
            }
        }
    }
    __syncthreads();

    // 3. scan from the top: find bin T where cumulative count reaches cutoff.
    if (t < 256) {
        uint32_t s = 0;
        for (int k = 0; k < 16; ++k) s += hist[t * 16 + k];
        csum[t] = s;
    }
    __syncthreads();
    if (t == 0) {
        uint32_t cum = 0; int tc = -1;
        for (int c = 255; c >= 0; --c) {
            if (cum + csum[c] >= cutoff) { tc = c; break; }
            cum += csum[c];
        }
        int T = -1; uint32_t base = 0;
        if (tc >= 0) {
            for (int k = 15; k >= 0; --k) {
                int bin = tc * 16 + k;
                uint32_t h = hist[bin];
                if (cum + h >= cutoff) { T = bin; base = cum; break; }
                cum += h;
            }
        }
        sT = T; sBase = base;
    }
    __syncthreads();
    int T = sT;
    if (T < 0) return;             // row has < cutoff label-0 -> keep all

    // 4. disable pass: bin<T -> disabled; bin==T -> collect for exact resolve.
    for (int i = t; i < NN; i += 1024) {
        uint32_t idx = (uint32_t)(b * NN + i);
        uint32_t u; bool is0;
        if (rnk) {
            uint32_t v = rnk[idx];
            is0 = ((v & 3u) == 2u); u = v >> 2;
        } else {
            is0 = (out[(size_t)idx * 5] == 0.0f);
            u = is0 ? (threefry_bits(idx) >> 9) : 0u;
        }
        if (is0) {
            int bin = (int)(u >> 11);
            if (bin < T) out[(size_t)idx * 5] = -1.0f;
            else if (bin == T) {
                uint32_t p_ = atomicAdd(&scnt, 1u);
                if (p_ < CAP) { lu[p_] = u; ln[p_] = (uint32_t)i; }
            }
        }
    }
    __syncthreads();

    // 5. exact rank resolution inside the boundary bin (expected ~9 entries).
    uint32_t cnt = scnt; if (cnt > CAP) cnt = CAP;
    uint32_t baseRank = sBase;
    for (uint32_t i = t; i < cnt; i += 1024) {
        uint32_t u = lu[i], n = ln[i];
        uint32_t r = baseRank;
        for (uint32_t j = 0; j < cnt; ++j) {
            // descending u, ties by smaller index first (stable argsort)
            r += (lu[j] > u || (lu[j] == u && ln[j] < n)) ? 1u : 0u;
        }
        if (r >= cutoff) out[((size_t)b * NN + n) * 5] = -1.0f;
    }
}

extern "C" void kernel_launch(void* const* d_in, const int* in_sizes, int n_in,
                              void* d_out, int out_size, void* d_ws, size_t ws_size,
                              hipStream_t stream) {
    // d_in[0] = cls_scores (shape-relevant only, never read)
    const float4* gt  = (const float4*)d_in[1];
    const float4* anc = (const float4*)d_in[2];
    float* out = (float*)d_out;
    uint32_t* w = (uint32_t*)d_ws;
    uint32_t* rnk = (ws_size >= WS_NEED) ? (w + WS_RNK) : (uint32_t*)nullptr;

    k_main<<<dim3(NBLK, NB), 256, 0, stream>>>(gt, anc, out, w, rnk);
    k_post<<<dim3(NB), 1024, 0, stream>>>(out, w, rnk);
}